// Round 16
// baseline (43.175 us; speedup 1.0000x reference)
//
#include <hip/hip_runtime.h>
#include <math.h>

#define B_  16
#define T_  16
#define N_  256
#define D_  384
#define Q_  384
#define K_  16
#define BT_ (B_ * T_)

// R16: cut per-CU L1-fill traffic (the hidden floor). R14's single block read
// patch(393KB) + FULL W_in(576KB) + FULL W_out(576KB) = 1.54MB through one
// CU's L1. K1/K3 batch the weight GEMVs: block = (48-col W slice) x (8 bt),
// so W traffic/block = 73KB and aggregate W L2->L1 traffic drops 295MB->37MB.
// K2 keeps the proven R7 scores pipeline + R14 key-rank topk + wsum.
// ws: qp[BT_*D_] | od[BT_*D_].

// ---------------------------------------------------------------------------
// K1: qp = queries @ W_in + b_in, batched. grid(8 dtiles, 32 bttiles) x 384.
// thread: s=tid/96 (4-way split-K over q), slot=tid%96 -> (r=slot/12 bt row,
// c4=slot%12 float4 col). 96 float4 W loads per thread.
// ---------------------------------------------------------------------------
__global__ __launch_bounds__(384)
void qproj_kernel(const float* __restrict__ queries,  // [BT_, Q_]
                  const float* __restrict__ W_in,     // [Q_, D_]
                  const float* __restrict__ b_in,     // [D_]
                  float* __restrict__ qp)             // [BT_, D_]
{
    const int dt  = blockIdx.x;             // 0..7  -> d0 = dt*48
    const int bt0 = blockIdx.y * 8;
    const int tid = threadIdx.x;            // 0..383

    __shared__ __align__(16) float s_q[8][Q_];        // 12 KB
    __shared__ __align__(16) float s_p4[4][8][48];    // 6 KB

    {   // stage 8 query rows (contiguous 12 KB)
        const float4* src = reinterpret_cast<const float4*>(queries + (size_t)bt0 * Q_);
        float4* dst = reinterpret_cast<float4*>(&s_q[0][0]);
        dst[tid] = src[tid];
        dst[tid + 384] = src[tid + 384];
    }
    __syncthreads();

    {
        const int s    = tid / 96;          // q-range [s*96, s*96+96)
        const int slot = tid % 96;
        const int r    = slot / 12;         // bt row 0..7
        const int c4   = slot % 12;         // float4 col
        const float* wp = W_in + (size_t)(s * 96) * D_ + dt * 48 + 4 * c4;
        float4 acc = {0.f, 0.f, 0.f, 0.f};
        #pragma unroll 4
        for (int qq = 0; qq < 96; ++qq) {
            const float4 w = *reinterpret_cast<const float4*>(wp + (size_t)qq * D_);
            const float qs = s_q[r][s * 96 + qq];
            acc.x += qs * w.x; acc.y += qs * w.y;
            acc.z += qs * w.z; acc.w += qs * w.w;
        }
        *reinterpret_cast<float4*>(&s_p4[s][r][4 * c4]) = acc;
    }
    __syncthreads();

    {   // combine 4 partials; 384 outputs = 8 bt x 48 cols
        const int r  = tid / 48;
        const int dc = tid % 48;
        const int d  = dt * 48 + dc;
        qp[(size_t)(bt0 + r) * D_ + d] = b_in[d]
            + s_p4[0][r][dc] + s_p4[1][r][dc] + s_p4[2][r][dc] + s_p4[3][r][dc];
    }
}

// ---------------------------------------------------------------------------
// K2: per bt: scores (R7 2-deep pipeline) -> key-rank topk -> wsum -> od.
// 256 blocks x 1024 threads.
// ---------------------------------------------------------------------------
__global__ __launch_bounds__(1024, 4)
void mid_kernel(const float* __restrict__ patch,   // [BT_, N_, D_]
                const float* __restrict__ qp,      // [BT_, D_]
                float* __restrict__ od)            // [BT_, D_]
{
    const int bt   = blockIdx.x;
    const int tid  = threadIdx.x;       // 0..1023
    const int lane = tid & 63;
    const int wave = tid >> 6;          // 0..15

    __shared__ __align__(16) float s_qp[D_];
    __shared__ __align__(16) float s_sc[N_];
    __shared__ __align__(16) unsigned s_ku[N_];
    __shared__ __align__(16) int   s_cnt4[N_][4];
    __shared__ float s_red[4];
    __shared__ float s_red2[4][2];
    __shared__ float s_w[K_];
    __shared__ int   s_ix[K_];

    const float* __restrict__ ptile = patch + (size_t)bt * N_ * D_;

    if (tid < D_) s_qp[tid] = qp[(size_t)bt * D_ + tid];
    __syncthreads();

    const int g16 = lane >> 4;          // 0..3
    const int sl  = lane & 15;
    const int n0  = wave * 4 + g16;     // rows n0 + {0,64,128,192}

    float4 A[6], Bu[6];

#define LOADROW(dst, it) {                                                     \
        const float* pr = ptile + (size_t)(n0 + (it) * 64) * D_;               \
        _Pragma("unroll")                                                      \
        for (int c = 0; c < 6; ++c)                                            \
            dst[c] = *reinterpret_cast<const float4*>(pr + c * 64 + 4 * sl); }

#define DOTSTORE(src, it) {                                                    \
        float p = 0.f;                                                         \
        _Pragma("unroll")                                                      \
        for (int c = 0; c < 6; ++c)                                            \
            p += src[c].x * qv[c].x + src[c].y * qv[c].y                       \
               + src[c].z * qv[c].z + src[c].w * qv[c].w;                      \
        _Pragma("unroll")                                                      \
        for (int off = 8; off; off >>= 1) p += __shfl_xor(p, off, 16);         \
        if (sl == 0) {                                                         \
            const int nn = n0 + (it) * 64;                                     \
            s_sc[nn] = p;                                                      \
            const unsigned u = __float_as_uint(p);                             \
            const unsigned ord = u ^ ((unsigned)((int)u >> 31) | 0x80000000u); \
            s_ku[nn] = (ord & 0xFFFFFF00u) | (255u - (unsigned)nn);            \
        } }

    {   // 2-deep pipelined stream (R7-proven)
        const float4* s_qp4 = reinterpret_cast<const float4*>(s_qp);
        float4 qv[6];
        #pragma unroll
        for (int c = 0; c < 6; ++c) qv[c] = s_qp4[c * 16 + sl];

        LOADROW(A, 0)
        LOADROW(Bu, 1)
        DOTSTORE(A, 0)
        LOADROW(A, 2)
        DOTSTORE(Bu, 1)
        LOADROW(Bu, 3)
        DOTSTORE(A, 2)
        DOTSTORE(Bu, 3)
    }
#undef LOADROW
#undef DOTSTORE
    __syncthreads();

    // ---- block max + key rank counts ----
    if (tid < N_) {
        float v = s_sc[tid];
        #pragma unroll
        for (int off = 32; off; off >>= 1) v = fmaxf(v, __shfl_xor(v, off));
        if (lane == 0) s_red[wave] = v;
    }
    {
        const int i   = tid >> 2;
        const int sub = tid & 3;
        const unsigned ki = s_ku[i];
        const uint4* k4 = reinterpret_cast<const uint4*>(s_ku);
        int c = 0;
        #pragma unroll
        for (int jj = 0; jj < 16; ++jj) {
            const int jr = (jj + sub * 4) & 15;
            const uint4 v = k4[sub * 16 + jr];
            c += (int)(v.x > ki) + (int)(v.y > ki)
               + (int)(v.z > ki) + (int)(v.w > ki);
        }
        s_cnt4[i][sub] = c;
    }
    __syncthreads();

    // ---- e, Z, SK ----
    float e = 0.f;
    int   cnt = N_;
    if (tid < N_) {
        const float mx = fmaxf(fmaxf(s_red[0], s_red[1]), fmaxf(s_red[2], s_red[3]));
        const int4 c4 = reinterpret_cast<const int4*>(s_cnt4)[tid];
        cnt = c4.x + c4.y + c4.z + c4.w;
        e = __expf(s_sc[tid] - mx);

        float z  = e;
        float sk = (cnt < K_) ? e : 0.f;
        #pragma unroll
        for (int off = 32; off; off >>= 1) {
            z  += __shfl_xor(z, off);
            sk += __shfl_xor(sk, off);
        }
        if (lane == 0) { s_red2[wave][0] = z; s_red2[wave][1] = sk; }
    }
    __syncthreads();

    {
        const float Z  = s_red2[0][0] + s_red2[1][0] + s_red2[2][0] + s_red2[3][0];
        const float SK = s_red2[0][1] + s_red2[1][1] + s_red2[2][1] + s_red2[3][1];
        const float inv = 1.f / (SK + 1e-8f * Z);
        if (tid < N_ && cnt < K_) {
            s_ix[cnt] = tid;
            s_w[cnt]  = e * inv;
        }
    }
    __syncthreads();

    // ---- weighted sum over K rows (L2-hot), 4 chains -> od ----
    if (tid < D_) {
        float a0 = 0.f, a1 = 0.f, a2 = 0.f, a3 = 0.f;
        #pragma unroll
        for (int j = 0; j < K_; j += 4) {
            a0 += s_w[j + 0] * ptile[(size_t)s_ix[j + 0] * D_ + tid];
            a1 += s_w[j + 1] * ptile[(size_t)s_ix[j + 1] * D_ + tid];
            a2 += s_w[j + 2] * ptile[(size_t)s_ix[j + 2] * D_ + tid];
            a3 += s_w[j + 3] * ptile[(size_t)s_ix[j + 3] * D_ + tid];
        }
        od[(size_t)bt * D_ + tid] = (a0 + a1) + (a2 + a3);
    }
}

// ---------------------------------------------------------------------------
// K3: out = od @ W_out + b_out, batched. grid(8 qtiles, 32 bttiles) x 384.
// ---------------------------------------------------------------------------
__global__ __launch_bounds__(384)
void outproj_kernel(const float* __restrict__ od,      // [BT_, D_]
                    const float* __restrict__ W_out,   // [D_, Q_]
                    const float* __restrict__ b_out,   // [Q_]
                    float* __restrict__ out)           // [BT_, Q_]
{
    const int qt  = blockIdx.x;             // 0..7 -> q0 = qt*48
    const int bt0 = blockIdx.y * 8;
    const int tid = threadIdx.x;            // 0..383

    __shared__ __align__(16) float s_o[8][D_];        // 12 KB
    __shared__ __align__(16) float s_p4[4][8][48];    // 6 KB

    {   // stage 8 od rows
        const float4* src = reinterpret_cast<const float4*>(od + (size_t)bt0 * D_);
        float4* dst = reinterpret_cast<float4*>(&s_o[0][0]);
        dst[tid] = src[tid];
        dst[tid + 384] = src[tid + 384];
    }
    __syncthreads();

    {
        const int s    = tid / 96;          // d-range [s*96, s*96+96)
        const int slot = tid % 96;
        const int r    = slot / 12;
        const int c4   = slot % 12;
        const float* wp = W_out + (size_t)(s * 96) * Q_ + qt * 48 + 4 * c4;
        float4 acc = {0.f, 0.f, 0.f, 0.f};
        #pragma unroll 4
        for (int dd = 0; dd < 96; ++dd) {
            const float4 w = *reinterpret_cast<const float4*>(wp + (size_t)dd * Q_);
            const float ov = s_o[r][s * 96 + dd];
            acc.x += ov * w.x; acc.y += ov * w.y;
            acc.z += ov * w.z; acc.w += ov * w.w;
        }
        *reinterpret_cast<float4*>(&s_p4[s][r][4 * c4]) = acc;
    }
    __syncthreads();

    {
        const int r  = tid / 48;
        const int qc = tid % 48;
        const int q  = qt * 48 + qc;
        out[(size_t)(bt0 + r) * Q_ + q] = b_out[q]
            + s_p4[0][r][qc] + s_p4[1][r][qc] + s_p4[2][r][qc] + s_p4[3][r][qc];
    }
}

extern "C" void kernel_launch(void* const* d_in, const int* in_sizes, int n_in,
                              void* d_out, int out_size, void* d_ws, size_t ws_size,
                              hipStream_t stream) {
    const float* queries = (const float*)d_in[0];
    const float* patch   = (const float*)d_in[1];
    const float* W_in    = (const float*)d_in[2];
    const float* b_in    = (const float*)d_in[3];
    const float* W_out   = (const float*)d_in[4];
    const float* b_out   = (const float*)d_in[5];
    float* out = (float*)d_out;

    float* qp = (float*)d_ws;                 // [BT_, D_]
    float* od = qp + (size_t)BT_ * D_;        // [BT_, D_]

    qproj_kernel<<<dim3(8, 32), dim3(384), 0, stream>>>(queries, W_in, b_in, qp);
    mid_kernel<<<dim3(BT_), dim3(1024), 0, stream>>>(patch, qp, od);
    outproj_kernel<<<dim3(8, 32), dim3(384), 0, stream>>>(od, W_out, b_out, out);
}

// Round 17
// 31.920 us; speedup vs baseline: 1.3526x; 1.3526x over previous
//
#include <hip/hip_runtime.h>
#include <math.h>

#define B_  16
#define T_  16
#define N_  256
#define D_  384
#define Q_  384
#define K_  16
#define BT_ (B_ * T_)

typedef float f32x4 __attribute__((ext_vector_type(4)));

// R17 = R14 (best, 32.67us) + NON-TEMPORAL patch loads in the scores phase.
// Theory: 32 concurrent blocks/XCD stream 12.5MB patch through the shared
// 4MB L2, evicting W_in/W_out -> every block re-fetches 1.15MB of weights
// from L3 (~290MB/invocation of L3 traffic; L3 ~10TB/s is the hidden wall).
// nt loads make the patch stream evict-first, keeping weights L2-resident.
__global__ __launch_bounds__(1024, 4)
void fused_kernel(const float* __restrict__ queries,  // [BT_, Q_]
                  const float* __restrict__ patch,    // [BT_, N_, D_]
                  const float* __restrict__ W_in,     // [Q_, D_]
                  const float* __restrict__ b_in,     // [D_]
                  const float* __restrict__ W_out,    // [D_, Q_]
                  const float* __restrict__ b_out,    // [Q_]
                  float* __restrict__ out)            // [BT_, Q_]
{
    const int bt   = blockIdx.x;
    const int tid  = threadIdx.x;       // 0..1023
    const int lane = tid & 63;
    const int wave = tid >> 6;          // 0..15

    __shared__ __align__(16) float s_q[Q_];
    __shared__ __align__(16) float s_qp[D_];
    __shared__ __align__(16) float s_sc[N_];
    __shared__ __align__(16) unsigned s_ku[N_];   // rank keys
    __shared__ __align__(16) int   s_cnt4[N_][4];
    __shared__ float s_red[4];
    __shared__ float s_red2[4][2];
    __shared__ float s_w[K_];
    __shared__ int   s_ix[K_];
    __shared__ __align__(16) float s_p8[8][D_];   // split-K partials (reused)
    __shared__ __align__(16) float s_od[D_];

    const float* __restrict__ ptile = patch + (size_t)bt * N_ * D_;

    // ---- stage query row ----
    if (tid < Q_) s_q[tid] = queries[(size_t)bt * Q_ + tid];
    __syncthreads();

    const int g16 = lane >> 4;          // 0..3
    const int sl  = lane & 15;
    const int n0  = wave * 4 + g16;     // rows n0 + {0,64,128,192}

    f32x4 A[6], Bu[6], C[6];

#define LOADROW(dst, it) {                                                     \
        const float* pr = ptile + (size_t)(n0 + (it) * 64) * D_;               \
        _Pragma("unroll")                                                      \
        for (int c = 0; c < 6; ++c)                                            \
            dst[c] = __builtin_nontemporal_load(                               \
                reinterpret_cast<const f32x4*>(pr + c * 64 + 4 * sl)); }

#define DOTSTORE(src, it) {                                                    \
        float p = 0.f;                                                         \
        _Pragma("unroll")                                                      \
        for (int c = 0; c < 6; ++c)                                            \
            p += src[c].x * qv[c].x + src[c].y * qv[c].y                       \
               + src[c].z * qv[c].z + src[c].w * qv[c].w;                      \
        _Pragma("unroll")                                                      \
        for (int off = 8; off; off >>= 1) p += __shfl_xor(p, off, 16);         \
        if (sl == 0) {                                                         \
            const int nn = n0 + (it) * 64;                                     \
            s_sc[nn] = p;                                                      \
            const unsigned u = __float_as_uint(p);                             \
            const unsigned ord = u ^ ((unsigned)((int)u >> 31) | 0x80000000u); \
            s_ku[nn] = (ord & 0xFFFFFF00u) | (255u - (unsigned)nn);            \
        } }

    // ---- issue patch prefetch rows 0,1,2 (independent of q_proj) ----
    LOADROW(A, 0)
    LOADROW(Bu, 1)
    LOADROW(C, 2)
    __builtin_amdgcn_sched_barrier(0);  // pin prefetch issue before qproj

    // ---- q_proj while prefetch streams: 768 thr, 8-way split-K, float4 W ----
    if (tid < 768) {
        const int s = tid / 96;         // k-split 0..7 -> q in [s*48, s*48+48)
        const int g = tid % 96;         // output cols 4g..4g+3
        float4 acc = {0.f, 0.f, 0.f, 0.f};
        const float* wp = W_in + (size_t)(s * 48) * D_ + 4 * g;
        #pragma unroll 4
        for (int qq = 0; qq < 48; ++qq) {
            const float4 w = *reinterpret_cast<const float4*>(wp + (size_t)qq * D_);
            const float qs = s_q[s * 48 + qq];
            acc.x += qs * w.x; acc.y += qs * w.y;
            acc.z += qs * w.z; acc.w += qs * w.w;
        }
        *reinterpret_cast<float4*>(&s_p8[s][4 * g]) = acc;
    }
    __syncthreads();
    if (tid < D_) {
        float v = b_in[tid];
        #pragma unroll
        for (int s = 0; s < 8; ++s) v += s_p8[s][tid];
        s_qp[tid] = v;
    }
    __syncthreads();   // prefetch has arrived under qproj

    // ---- scores: rows 0,1,2 from prefetch; row 3 pipelined ----
    {
        const f32x4* s_qp4 = reinterpret_cast<const f32x4*>(s_qp);
        f32x4 qv[6];
        #pragma unroll
        for (int c = 0; c < 6; ++c) qv[c] = s_qp4[c * 16 + sl];

        DOTSTORE(A, 0)
        LOADROW(A, 3)
        DOTSTORE(Bu, 1)
        DOTSTORE(C, 2)
        DOTSTORE(A, 3)
    }
#undef LOADROW
#undef DOTSTORE
    __syncthreads();

    // ---- block max (waves 0-3) + key rank counts (all 1024 thr, rotated) ----
    if (tid < N_) {
        float v = s_sc[tid];
        #pragma unroll
        for (int off = 32; off; off >>= 1) v = fmaxf(v, __shfl_xor(v, off));
        if (lane == 0) s_red[wave] = v;
    }
    {
        const int i   = tid >> 2;       // 0..255
        const int sub = tid & 3;        // chunk [sub*64, sub*64+64)
        const unsigned ki = s_ku[i];
        const uint4* k4 = reinterpret_cast<const uint4*>(s_ku);
        int c = 0;
        #pragma unroll
        for (int jj = 0; jj < 16; ++jj) {
            const int jr = (jj + sub * 4) & 15;          // rotate start
            const uint4 v = k4[sub * 16 + jr];
            c += (int)(v.x > ki) + (int)(v.y > ki)
               + (int)(v.z > ki) + (int)(v.w > ki);
        }
        s_cnt4[i][sub] = c;
    }
    __syncthreads();

    // ---- e, Z, SK (threads < 256) ----
    float e = 0.f;
    int   cnt = N_;
    if (tid < N_) {
        const float mx = fmaxf(fmaxf(s_red[0], s_red[1]), fmaxf(s_red[2], s_red[3]));
        const int4 c4 = reinterpret_cast<const int4*>(s_cnt4)[tid];
        cnt = c4.x + c4.y + c4.z + c4.w;
        e = __expf(s_sc[tid] - mx);

        float z  = e;
        float sk = (cnt < K_) ? e : 0.f;
        #pragma unroll
        for (int off = 32; off; off >>= 1) {
            z  += __shfl_xor(z, off);
            sk += __shfl_xor(sk, off);
        }
        if (lane == 0) { s_red2[wave][0] = z; s_red2[wave][1] = sk; }
    }
    __syncthreads();

    // weight_i = softmax_i / (sum_topk + EPS) = e_i / (SK + EPS*Z)
    {
        const float Z  = s_red2[0][0] + s_red2[1][0] + s_red2[2][0] + s_red2[3][0];
        const float SK = s_red2[0][1] + s_red2[1][1] + s_red2[2][1] + s_red2[3][1];
        const float inv = 1.f / (SK + 1e-8f * Z);
        if (tid < N_ && cnt < K_) {
            s_ix[cnt] = tid;
            s_w[cnt]  = e * inv;
        }
    }
    __syncthreads();

    // ---- W_out prefetch (independent of s_od) + weighted sum over K rows ----
    float4 wpre[8];
    const float* wp = W_out;
    if (tid < 768) {
        const int s = tid / 96;
        const int g = tid % 96;
        wp = W_out + (size_t)(s * 48) * Q_ + 4 * g;
        #pragma unroll
        for (int p = 0; p < 8; ++p)
            wpre[p] = *reinterpret_cast<const float4*>(wp + (size_t)p * Q_);
    }
    __builtin_amdgcn_sched_barrier(0);  // issue W_out loads before wsum

    if (tid < D_) {
        float a0 = 0.f, a1 = 0.f, a2 = 0.f, a3 = 0.f;
        #pragma unroll
        for (int j = 0; j < K_; j += 4) {
            a0 += s_w[j + 0] * ptile[(size_t)s_ix[j + 0] * D_ + tid];
            a1 += s_w[j + 1] * ptile[(size_t)s_ix[j + 1] * D_ + tid];
            a2 += s_w[j + 2] * ptile[(size_t)s_ix[j + 2] * D_ + tid];
            a3 += s_w[j + 3] * ptile[(size_t)s_ix[j + 3] * D_ + tid];
        }
        s_od[tid] = (a0 + a1) + (a2 + a3);
    }
    __syncthreads();

    // ---- out-proj: 768 thr, 8-way split-K; 8 prefetched + 40 streamed ----
    if (tid < 768) {
        const int s = tid / 96;
        const int g = tid % 96;
        const int base = s * 48;
        float4 acc = {0.f, 0.f, 0.f, 0.f};
        #pragma unroll
        for (int p = 0; p < 8; ++p) {
            const float ov = s_od[base + p];
            acc.x += ov * wpre[p].x; acc.y += ov * wpre[p].y;
            acc.z += ov * wpre[p].z; acc.w += ov * wpre[p].w;
        }
        #pragma unroll 4
        for (int dd = 8; dd < 48; ++dd) {
            const float4 w = *reinterpret_cast<const float4*>(wp + (size_t)dd * Q_);
            const float ov = s_od[base + dd];
            acc.x += ov * w.x; acc.y += ov * w.y;
            acc.z += ov * w.z; acc.w += ov * w.w;
        }
        *reinterpret_cast<float4*>(&s_p8[s][4 * g]) = acc;
    }
    __syncthreads();
    if (tid < Q_) {
        float v = b_out[tid];
        #pragma unroll
        for (int s = 0; s < 8; ++s) v += s_p8[s][tid];
        out[(size_t)bt * Q_ + tid] = v;
    }
}

extern "C" void kernel_launch(void* const* d_in, const int* in_sizes, int n_in,
                              void* d_out, int out_size, void* d_ws, size_t ws_size,
                              hipStream_t stream) {
    const float* queries = (const float*)d_in[0];
    const float* patch   = (const float*)d_in[1];
    const float* W_in    = (const float*)d_in[2];
    const float* b_in    = (const float*)d_in[3];
    const float* W_out   = (const float*)d_in[4];
    const float* b_out   = (const float*)d_in[5];
    float* out = (float*)d_out;

    fused_kernel<<<dim3(BT_), dim3(1024), 0, stream>>>(
        queries, patch, W_in, b_in, W_out, b_out, out);
}